// Round 6
// baseline (126.706 us; speedup 1.0000x reference)
//
#include <hip/hip_runtime.h>

// RetinaNet matcher: gt_boxes [B=8, G=64, 4] f32, anchors [A=120000, 4] f32.
// Outputs (concatenated in d_out, f32): matched_idxs [B,A] (as float), matched_vals [B,A].
//
// Numerics (verified bit-exact in R5, absmax 0.0): opaque() value barriers on
// every mul result leave zero legal FMA-contraction sites, so every op is a
// single deterministic IEEE instruction; pass1 bits == pass2 bits == np bits
// independent of kernel shape. argmax tie-break = first (lowest g). IoU >= 0,
// so per-gt max reduces bit-exactly via atomicMax on the uint bit pattern.
//
// R6: pass1 takes pass2's shape (it's measurably faster per IoU): per-lane
// anchors from coalesced float4 VMEM, fully-unrolled g-loop with uniform
// s_load of gt, per-lane m[64] accumulator registers (static indexing only).
// Cross-lane reduce happens ONCE per wave (6-stage butterfly over 64 regs),
// not per g-iteration (R3's mistake). Invalid anchors use degenerate boxes
// (-3e38 corners) -> IoU == 0 exactly, no NaN (denom = garea > 0).

static constexpr int G = 64;

__device__ __forceinline__ float opaque(float x) {
    asm volatile("" : "+v"(x));  // no-op; blocks FMA contraction across x
    return x;
}

__device__ __forceinline__ float box_area(float x1, float y1, float x2, float y2) {
    return opaque(__fmul_rn(__fsub_rn(x2, x1), __fsub_rn(y2, y1)));
}

__device__ __forceinline__ float iou_f(float gx1, float gy1, float gx2, float gy2,
                                       float garea,
                                       float ax1, float ay1, float ax2, float ay2,
                                       float aarea) {
    float ltx = fmaxf(gx1, ax1);
    float lty = fmaxf(gy1, ay1);
    float rbx = fminf(gx2, ax2);
    float rby = fminf(gy2, ay2);
    float w = fmaxf(__fsub_rn(rbx, ltx), 0.0f);
    float h = fmaxf(__fsub_rn(rby, lty), 0.0f);
    float inter = opaque(__fmul_rn(w, h));
    float denom = __fsub_rn(__fadd_rn(garea, aarea), inter);  // no fusable mul feeds this
    return __fdiv_rn(inter, denom);
}

__global__ void init_hpg(unsigned int* hpg, int n) {
    int i = blockIdx.x * blockDim.x + threadIdx.x;
    if (i < n) hpg[i] = 0u;  // 0u == 0.0f bits; IoU >= 0
}

// Pass 1: per-thread m[64] running max over its 4 anchors (per-lane VGPR data,
// gt via uniform s_load). One butterfly reduce per wave at the end, then
// 64 LDS atomics (lane 0) and 64 global atomics (t<64) per block.
// Block: 256 threads x 4 anchors = 1024 anchors/block. Grid: (ceil(A/1024), B).
__global__ __launch_bounds__(256, 2)
void pass1_hpg(const float* __restrict__ gt,
               const float* __restrict__ anchors,
               unsigned int* __restrict__ hpg, int A) {
    const int b = blockIdx.y;
    const int t = threadIdx.x;

    __shared__ unsigned int sred[G];
    if (t < G) sred[t] = 0u;
    __syncthreads();

    const float4* gtb = (const float4*)(gt + (size_t)b * G * 4);

    float m[G];
#pragma unroll
    for (int g = 0; g < G; ++g) m[g] = 0.0f;

    const int base = blockIdx.x * 1024;
    for (int k = 0; k < 4; ++k) {               // anchor loop: NOT unrolled (I$)
        int a = base + k * 256 + t;
        bool v = (a < A);
        const float4 ab = ((const float4*)anchors)[v ? a : 0];
        float ax1 = v ? ab.x : -3.0e38f;
        float ay1 = v ? ab.y : -3.0e38f;
        float ax2 = v ? ab.z : -3.0e38f;
        float ay2 = v ? ab.w : -3.0e38f;
        float aar = box_area(ax1, ay1, ax2, ay2);   // 0 for degenerate box

#pragma unroll
        for (int g = 0; g < G; ++g) {           // fully unrolled: m[g] static
            const float4 gb = gtb[g];           // uniform -> s_load, K$-hot
            float ga = box_area(gb.x, gb.y, gb.z, gb.w);
            float q = iou_f(gb.x, gb.y, gb.z, gb.w, ga,
                            ax1, ay1, ax2, ay2, aar);
            m[g] = fmaxf(m[g], q);              // degenerate -> q==0, no-op
        }
    }

    // one cross-lane butterfly for all 64 accumulators (exact: max assoc.)
#pragma unroll
    for (int st = 0; st < 6; ++st) {
#pragma unroll
        for (int g = 0; g < G; ++g)
            m[g] = fmaxf(m[g], __shfl_xor(m[g], 1 << st, 64));
    }

    if ((t & 63) == 0) {                        // one lane per wave
#pragma unroll
        for (int g = 0; g < G; ++g)
            atomicMax(&sred[g], __float_as_uint(m[g]));
    }
    __syncthreads();
    if (t < G) atomicMax(&hpg[b * G + t], sred[t]);
}

// Pass 2 (unchanged from R5, bit-exact): per anchor -> max/argmax over g,
// thresholds, low-quality recovery. gt/hpg via uniform s_load; anchors
// per-lane in VGPRs. 2 anchors/thread. Grid: (ceil(A/512), B).
__global__ __launch_bounds__(256, 8)
void pass2_match(const float* __restrict__ gt,
                 const float* __restrict__ anchors,
                 const unsigned int* __restrict__ hpg,
                 float* __restrict__ out_idx,
                 float* __restrict__ out_val, int A) {
    const int b = blockIdx.y;
    const int t = threadIdx.x;

    const int base = blockIdx.x * 512;
    float ax1[2], ay1[2], ax2[2], ay2[2], aar[2];
    bool val[2];
#pragma unroll
    for (int k = 0; k < 2; ++k) {
        int a = base + k * 256 + t;
        val[k] = (a < A);
        int aa = val[k] ? a : 0;
        const float4 ab = ((const float4*)anchors)[aa];
        ax1[k] = ab.x; ay1[k] = ab.y; ax2[k] = ab.z; ay2[k] = ab.w;
        aar[k] = box_area(ab.x, ab.y, ab.z, ab.w);
    }

    const float4* gtb = (const float4*)(gt + (size_t)b * G * 4);
    const unsigned int* hpgb = hpg + b * G;

    float vmax[2] = {-1.0f, -1.0f};
    int amax[2] = {0, 0};
    bool pu[2] = {false, false};
#pragma unroll 4
    for (int g = 0; g < G; ++g) {
        const float4 gb = gtb[g];                       // uniform -> s_load
        float ga = box_area(gb.x, gb.y, gb.z, gb.w);
        float hg = __uint_as_float(hpgb[g]);            // uniform -> s_load
#pragma unroll
        for (int k = 0; k < 2; ++k) {
            float q = iou_f(gb.x, gb.y, gb.z, gb.w, ga,
                            ax1[k], ay1[k], ax2[k], ay2[k], aar[k]);
            if (q > vmax[k]) { vmax[k] = q; amax[k] = g; }  // first-max tie-break
            pu[k] = pu[k] || (q == hg);
        }
    }

#pragma unroll
    for (int k = 0; k < 2; ++k) {
        int a = base + k * 256 + t;
        if (!val[k]) continue;
        int m;
        if (pu[k]) {
            m = amax[k];                    // low-quality match recovery
        } else if (vmax[k] < 0.4f) {
            m = -1;                         // BELOW_LOW_QUALITY
        } else if (vmax[k] < 0.5f) {
            m = -2;                         // BETWEEN_THRESHOLDS
        } else {
            m = amax[k];
        }
        size_t o = (size_t)b * A + a;
        out_idx[o] = (float)m;
        out_val[o] = vmax[k];
    }
}

extern "C" void kernel_launch(void* const* d_in, const int* in_sizes, int n_in,
                              void* d_out, int out_size, void* d_ws, size_t ws_size,
                              hipStream_t stream) {
    const float* gt = (const float*)d_in[0];
    const float* anchors = (const float*)d_in[1];
    const int BG = in_sizes[0] / 4;   // B*G = 512
    const int B = BG / G;             // 8
    const int A = in_sizes[1] / 4;    // 120000

    unsigned int* hpg = (unsigned int*)d_ws;  // B*G uints = 2 KB
    float* out_idx = (float*)d_out;
    float* out_val = out_idx + (size_t)B * A;

    init_hpg<<<(BG + 255) / 256, 256, 0, stream>>>(hpg, BG);

    dim3 g1((A + 1023) / 1024, B);
    pass1_hpg<<<g1, 256, 0, stream>>>(gt, anchors, hpg, A);

    dim3 g2((A + 511) / 512, B);
    pass2_match<<<g2, 256, 0, stream>>>(gt, anchors, hpg, out_idx, out_val, A);
}